// Round 7
// baseline (226.147 us; speedup 1.0000x reference)
//
#include <hip/hip_runtime.h>
#include <math.h>

// ComplexEMA: B=2, D=1024, N=16, L=4096.
// y[b,d,l] = Re( sum_n gp[d,n] * h[d,n,l] ) + omega[d]*x[b,d,l]
//   h[n,l] = q[n]*h[n,l-1] + x[l]
// v4: 2 waves per channel (block=128, 32 elems/lane) -> 4096 waves = 4/SIMD
//     occupancy (was 2/SIMD, VALUBusy stuck ~52% = latency-bound half-idle).
//     Two-level scan: 6-step KS within wave (multiplier q^32 ladder from LDS)
//     + one LDS exchange, wave1 folds wave0's lane-lambda prefix with q^2048.
//     No x LDS staging: per-lane contiguous global float4, pipelined 1 ahead;
//     pass C re-reads x from L2. Multiplier ladder in LDS keeps VGPR <= 128.

#define Bq 2
#define Dq 1024
#define Nq 16
#define Lq 4096
#define CH 32   // elements per lane

__global__ __launch_bounds__(128, 4) void cema_kernel(
    const float* __restrict__ x,
    const float* __restrict__ alpha,
    const float* __restrict__ delta,
    const float* __restrict__ theta,
    const float* __restrict__ gmr,
    const float* __restrict__ gmi,
    const float* __restrict__ omg,
    float* __restrict__ out)
{
    __shared__ float cqr[Nq], cqi[Nq], cgr[Nq], cgi[Nq];
    __shared__ float Ms[7][2][Nq];        // Ms[k] = (q^32)^(2^k); [6] = q^2048
    __shared__ float Pbuf[64][2 * Nq + 1]; // wave0 inclusive prefixes, stride 33

    const int bd  = blockIdx.x;           // 0..2047
    const int d   = bd & (Dq - 1);
    const int t   = threadIdx.x;          // 0..127
    const int w   = t >> 6;               // wave id 0/1
    const int lam = t & 63;               // lane in wave

    const float* xg = x   + (size_t)bd * Lq + t * CH;
    float*       yg = out + (size_t)bd * Lq + t * CH;

    // ---- coefficients + multiplier ladder (threads 0..15) ----
    if (t < Nq) {
        const int n = t;
        float th  = theta[d];
        float f   = 1.f / (1.f + expf(-th));
        float phi = (float)(n + 1) * f * (float)(2.0 * M_PI / 16.0);
        float a   = 1.f / (1.f + expf(-alpha[d * Nq + n]));
        float dd  = 1.f / (1.f + expf(-delta[d * Nq + n]));
        float radius = fminf(1.f - a * dd, 1.f);
        float s, c;
        sincosf(phi, &s, &c);
        float qrv = radius * c, qiv = radius * s;
        cqr[n] = qrv; cqi[n] = qiv;
        cgr[n] = gmr[d * Nq + n] * 0.25f * a;   // scale = 1/sqrt(16)
        cgi[n] = gmi[d * Nq + n] * 0.25f * a;
        float mr = qrv, mi = qiv;               // -> q^32 via 5 squarings
        #pragma unroll
        for (int k = 0; k < 5; ++k) { float t2 = mr*mr - mi*mi; mi = 2.f*mr*mi; mr = t2; }
        #pragma unroll
        for (int k = 0; k < 7; ++k) {           // ladder (q^32)^(2^k), k=0..6
            Ms[k][0][n] = mr; Ms[k][1][n] = mi;
            float t2 = mr*mr - mi*mi; mi = 2.f*mr*mi; mr = t2;
        }
    }
    __syncthreads();

    float qrr[Nq], qii[Nq], hr[Nq], hi_[Nq];
    #pragma unroll
    for (int n = 0; n < Nq; ++n) {
        qrr[n] = cqr[n]; qii[n] = cqi[n];
        hr[n] = 0.f; hi_[n] = 0.f;
    }

    // ---- pass A: local scan of own 32 elems (global float4, 1 ahead) ----
    {
        float4 cur = *reinterpret_cast<const float4*>(xg);
        for (int i = 0; i < 8; ++i) {
            int j = (i < 7) ? (i + 1) : 7;
            float4 nxt = *reinterpret_cast<const float4*>(xg + 4 * j);
            #pragma unroll
            for (int u = 0; u < 4; ++u) {
                float xe = (u == 0) ? cur.x : (u == 1) ? cur.y : (u == 2) ? cur.z : cur.w;
                #pragma unroll
                for (int n = 0; n < Nq; ++n) {
                    float nr = fmaf(qrr[n], hr[n], fmaf(-qii[n], hi_[n], xe));
                    float ni = fmaf(qrr[n], hi_[n], qii[n] * hr[n]);
                    hr[n] = nr; hi_[n] = ni;
                }
            }
            cur = nxt;
        }
    }

    // ---- KS scan within wave: 6 steps, multipliers from LDS ladder ----
    #pragma unroll
    for (int k = 0; k < 6; ++k) {
        const int s = 1 << k;
        #pragma unroll
        for (int n = 0; n < Nq; ++n) {
            float mr = Ms[k][0][n], mi = Ms[k][1][n];
            float ur = __shfl_up(hr[n], s, 64);
            float ui = __shfl_up(hi_[n], s, 64);
            float vr = fmaf(mr, ur, fmaf(-mi, ui, hr[n]));
            float vi = fmaf(mr, ui, fmaf(mi, ur, hi_[n]));
            bool p = (lam >= s);
            hr[n]  = p ? vr : hr[n];
            hi_[n] = p ? vi : hi_[n];
        }
    }

    // ---- cross-wave: wave0 publishes lane prefixes; wave1 folds q^2048 ----
    if (w == 0) {
        #pragma unroll
        for (int n = 0; n < Nq; ++n) {
            Pbuf[lam][2 * n]     = hr[n];
            Pbuf[lam][2 * n + 1] = hi_[n];
        }
    }
    __syncthreads();
    if (w == 1) {
        #pragma unroll
        for (int n = 0; n < Nq; ++n) {
            float mr = Ms[6][0][n], mi = Ms[6][1][n];
            float ur = Pbuf[lam][2 * n], ui = Pbuf[lam][2 * n + 1];
            hr[n]  = fmaf(mr, ur, fmaf(-mi, ui, hr[n]));
            hi_[n] = fmaf(mr, ui, fmaf(mi, ur, hi_[n]));
        }
    }

    // ---- exclusive carry ----
    #pragma unroll
    for (int n = 0; n < Nq; ++n) {
        float cr = __shfl_up(hr[n], 1, 64);
        float ci = __shfl_up(hi_[n], 1, 64);
        float br = 0.f, bi = 0.f;
        if (w == 1) { br = Pbuf[63][2 * n]; bi = Pbuf[63][2 * n + 1]; }
        hr[n]  = lam ? cr : br;
        hi_[n] = lam ? ci : bi;
    }

    // ---- pass C: re-run with carry, emit y ----
    float gpr[Nq], gpi[Nq];
    #pragma unroll
    for (int n = 0; n < Nq; ++n) { gpr[n] = cgr[n]; gpi[n] = cgi[n]; }
    const float om = omg[d];

    {
        float4 cur = *reinterpret_cast<const float4*>(xg);
        for (int i = 0; i < 8; ++i) {
            int j = (i < 7) ? (i + 1) : 7;
            float4 nxt = *reinterpret_cast<const float4*>(xg + 4 * j);
            float yo[4];
            #pragma unroll
            for (int u = 0; u < 4; ++u) {
                float xe = (u == 0) ? cur.x : (u == 1) ? cur.y : (u == 2) ? cur.z : cur.w;
                float f0 = om * xe, f1 = 0.f, f2 = 0.f, f3 = 0.f;
                #pragma unroll
                for (int n = 0; n < Nq; ++n) {
                    float nr = fmaf(qrr[n], hr[n], fmaf(-qii[n], hi_[n], xe));
                    float ni = fmaf(qrr[n], hi_[n], qii[n] * hr[n]);
                    hr[n] = nr; hi_[n] = ni;
                    if ((n & 3) == 0)      { f0 = fmaf(gpr[n], nr, f0); f0 = fmaf(-gpi[n], ni, f0); }
                    else if ((n & 3) == 1) { f1 = fmaf(gpr[n], nr, f1); f1 = fmaf(-gpi[n], ni, f1); }
                    else if ((n & 3) == 2) { f2 = fmaf(gpr[n], nr, f2); f2 = fmaf(-gpi[n], ni, f2); }
                    else                   { f3 = fmaf(gpr[n], nr, f3); f3 = fmaf(-gpi[n], ni, f3); }
                }
                yo[u] = (f0 + f1) + (f2 + f3);
            }
            *reinterpret_cast<float4*>(yg + 4 * i) = make_float4(yo[0], yo[1], yo[2], yo[3]);
            cur = nxt;
        }
    }
}

extern "C" void kernel_launch(void* const* d_in, const int* in_sizes, int n_in,
                              void* d_out, int out_size, void* d_ws, size_t ws_size,
                              hipStream_t stream) {
    const float* x     = (const float*)d_in[0];
    const float* alpha = (const float*)d_in[1];
    const float* delta = (const float*)d_in[2];
    const float* theta = (const float*)d_in[3];
    const float* gmr   = (const float*)d_in[4];
    const float* gmi   = (const float*)d_in[5];
    const float* omg   = (const float*)d_in[6];

    dim3 grid(Bq * Dq);
    dim3 block(128);
    cema_kernel<<<grid, block, 0, stream>>>(x, alpha, delta, theta, gmr, gmi, omg,
                                            (float*)d_out);
}